// Round 12
// baseline (115.181 us; speedup 1.0000x reference)
//
#include <hip/hip_runtime.h>
#include <hip/hip_bf16.h>
#include <math.h>

#define D 384
#define EPS 1e-8f

#define RPB 256            // rows per block (4 waves x 64) -- B-reuse preserved
#define CPS 256            // cols per split (32 splits)
#define POS_W 64           // cols per position: acc[4][4] = 64 AGPRs -> 3 waves/SIMD
#define NPOS 4             // 256/64
#define NKB 6              // 384/64 k-steps (i8: K=64 per MFMA)
#define NT  24             // NPOS * NKB tiles per block
#define STG 20480          // stage bytes: 4 KB B (64 cols x 64 B) + 16 KB A (256 rows x 64 B)

typedef int    intx4   __attribute__((ext_vector_type(4)));

// ---------------- kernel 1: i8 quant + qninv + ws init (R10, measured) ----------------
__global__ __launch_bounds__(256) void prep_kernel(const float* __restrict__ in,
                                                   float* __restrict__ qninv,
                                                   char* __restrict__ xq,
                                                   unsigned long long* __restrict__ best,
                                                   float* __restrict__ out, int N) {
    if (blockIdx.x == 0 && threadIdx.x == 0) *out = 0.f;   // replaces memset node
    int row = blockIdx.x * 4 + (threadIdx.x >> 6);   // one wave per row
    if (row >= N) return;
    int lane = threadIdx.x & 63;
    const float* p = in + (size_t)row * D;
    float4 a = *(const float4*)(p + lane * 4);           // elems 0..255
    float2 b = *(const float2*)(p + 256 + lane * 2);     // elems 256..383
    float s = a.x * a.x + a.y * a.y + a.z * a.z + a.w * a.w + b.x * b.x + b.y * b.y;
#pragma unroll
    for (int off = 32; off >= 1; off >>= 1) s += __shfl_xor(s, off, 64);
    float rn = 1.0f / fmaxf(sqrtf(s), EPS);
    const float sc = rn * 127.f;
    int b0 = __float2int_rn(a.x * sc), b1 = __float2int_rn(a.y * sc);
    int b2 = __float2int_rn(a.z * sc), b3 = __float2int_rn(a.w * sc);
    int b4 = __float2int_rn(b.x * sc), b5 = __float2int_rn(b.y * sc);
    char* q = xq + (size_t)row * D;
    *(int*)(q + lane * 4) = (b0 & 0xff) | ((b1 & 0xff) << 8) | ((b2 & 0xff) << 16) | (b3 << 24);
    *(short*)(q + 256 + lane * 2) = (short)((b4 & 0xff) | (b5 << 8));
    int qs = b0 * b0 + b1 * b1 + b2 * b2 + b3 * b3 + b4 * b4 + b5 * b5;
#pragma unroll
    for (int off = 32; off >= 1; off >>= 1) qs += __shfl_xor(qs, off, 64);
    if (lane == 0) { qninv[row] = 1.0f / sqrtf((float)qs); best[row] = 0ull; }
}

// ---------------- kernel 2: i8-MFMA scan, occupancy experiment ----------------
// R11 analysis: unified reg file -> acc[4][8](128 AGPR)+116 VGPR = 244/wave
// = 2 waves/SIMD cap; 40% of the step-slot is pure stall with nothing
// saturated. This round: POS_W=64 -> acc[4][4] (64 AGPR), total ~154 regs
// -> 3 waves/SIMD; 2-buffer 2-phase schedule (one vmcnt(0)+barrier per
// step, stage(tt+1) issued right after the barrier, latency hidden by
// this step's ds+MFMA and 3-blocks/CU TLP). LDS 2x20 KB = 40 KB/block.
// Cost accepted: A restaged per 64-col position (+~45% LDS traffic/unit);
// bet: occupancy 1.5x beats traffic 1.45x on a latency-bound kernel.
// WAR safety: stage(tt+1) writes buf[(tt+1)&1], last read at step tt-1;
// the barrier at the top of step tt orders all those reads before this
// write. vmcnt(0) at top of step tt retires stage(tt) (issued at tt-1,
// a full step of cover).
__global__ __launch_bounds__(256, 3) void maxdot_rows(const char* __restrict__ xq,
                                                      unsigned long long* __restrict__ best) {
    __shared__ char Bs[2][STG];

    const int t    = threadIdx.x;
    const int lane = t & 63;
    const int wv   = t >> 6;
    const int quad = lane >> 4, l16 = lane & 15;
    const int rb   = blockIdx.x >> 5;                // 32 row-blocks
    const int cs   = blockIdx.x & 31;                // 32 col-splits
    const int row0b = rb * RPB;
    const int col0s = cs * CPS;
    const int wrow0 = row0b + wv * 64;

    intx4 acc[4][4];
#pragma unroll
    for (int mi = 0; mi < 4; ++mi)
#pragma unroll
        for (int ni = 0; ni < 4; ++ni) acc[mi][ni] = (intx4){0, 0, 0, 0};

    int rv[16];
    int ri[16];
#pragma unroll
    for (int i = 0; i < 16; ++i) { rv[i] = -0x7fffffff; ri[i] = 0; }

    // staging (20 KB = 80 B/thread = 5 glds): B slot t (col t>>2, gran t&3);
    // A slots t+256j, j=0..3 (row (t>>2)+64j, gran t&3).
    const int sc = t >> 2;
    const int sg = t & 3;

#define GLDS(SRC, DST) __builtin_amdgcn_global_load_lds(                               \
        (const __attribute__((address_space(1))) void*)(SRC),                          \
        (__attribute__((address_space(3))) void*)(DST), 16, 0, 0)

#define STAGE(TT, BUF) do {                                                            \
        const int p_  = (TT) / NKB, kb_ = (TT) - p_ * NKB;                             \
        const int cb_ = col0s + p_ * POS_W;                                            \
        const size_t ko_ = (size_t)kb_ * 64 + sg * 16;                                 \
        GLDS(xq + (size_t)(cb_ + sc)        * 384 + ko_, (BUF) +         t * 16);      \
        GLDS(xq + (size_t)(row0b + sc)      * 384 + ko_, (BUF) +  4096 + t * 16);      \
        GLDS(xq + (size_t)(row0b + 64 + sc) * 384 + ko_, (BUF) +  8192 + t * 16);      \
        GLDS(xq + (size_t)(row0b + 128 + sc)* 384 + ko_, (BUF) + 12288 + t * 16);      \
        GLDS(xq + (size_t)(row0b + 192 + sc)* 384 + ko_, (BUF) + 16384 + t * 16);      \
    } while (0)

    // prologue: stage(0) in flight
    STAGE(0, Bs[0]);

    const int lofs = l16 * 64 + quad * 16;           // reader byte within a 64-B k-chunk

    for (int tt = 0; tt < NT; ++tt) {
        const int pos = tt / NKB, kb = tt - pos * NKB;
        const int colbase = col0s + pos * POS_W;
        char* bcur = Bs[tt & 1];

        // stage(tt) complete (issued one step ago); order prior reads of
        // buf[(tt+1)&1] before this step's STAGE into it
        asm volatile("s_waitcnt vmcnt(0)" ::: "memory");
        __builtin_amdgcn_s_barrier();
        __builtin_amdgcn_sched_barrier(0);

        // stage next tile into the other buffer (latency hides under this
        // step's ds_read+MFMA + cross-block TLP at 3 blocks/CU)
        if (tt + 1 < NT) STAGE(tt + 1, Bs[(tt + 1) & 1]);

        // A and B fragments from LDS; all 8 ds_reads issued together
        const char* Ab = bcur + 4096 + wv * 4096;    // this wave's 64 rows
        intx4 af[4];
#pragma unroll
        for (int mi = 0; mi < 4; ++mi)
            af[mi] = *(const intx4*)(Ab + mi * 1024 + lofs);
        intx4 bfr[4];
#pragma unroll
        for (int ni = 0; ni < 4; ++ni)
            bfr[ni] = *(const intx4*)(bcur + ni * 1024 + lofs);
#pragma unroll
        for (int mi = 0; mi < 4; ++mi)
#pragma unroll
            for (int ni = 0; ni < 4; ++ni)
                acc[mi][ni] = __builtin_amdgcn_mfma_i32_16x16x64_i8(af[mi], bfr[ni], acc[mi][ni], 0, 0, 0);

        // ---- end of a position: fold into running (val, col); zero acc ----
        if (kb == NKB - 1) {
            const bool dg = (colbase < row0b + RPB) && (row0b < colbase + POS_W);
#pragma unroll
            for (int mi = 0; mi < 4; ++mi)
#pragma unroll
                for (int reg = 0; reg < 4; ++reg) {
                    const int r = wrow0 + mi * 16 + quad * 4 + reg;
                    int d[4];
#pragma unroll
                    for (int ni = 0; ni < 4; ++ni) d[ni] = acc[mi][ni][reg];
                    if (dg) {
#pragma unroll
                        for (int ni = 0; ni < 4; ++ni)
                            if (colbase + ni * 16 + l16 == r) d[ni] = -0x40000000;
                    }
                    int m = d[0]; int ci = 0;
#pragma unroll
                    for (int ni = 1; ni < 4; ++ni) {     // ties -> lower ni (lower col)
                        bool gt = d[ni] > m;
                        m  = gt ? d[ni] : m;
                        ci = gt ? ni : ci;
                    }
                    const int slot = mi * 4 + reg;
                    bool upd = m > rv[slot];             // ties -> earlier position (lower col)
                    rv[slot] = upd ? m : rv[slot];
                    ri[slot] = upd ? (colbase + ci * 16 + l16) : ri[slot];
#pragma unroll
                    for (int ni = 0; ni < 4; ++ni) acc[mi][ni][reg] = 0;
                }
        }
    }
#undef STAGE
#undef GLDS

    // ---- final row-side reduce over the 16 col-lanes, one atomic per row ----
#pragma unroll
    for (int slot = 0; slot < 16; ++slot) {
        int v = rv[slot]; int ci = ri[slot];
#pragma unroll
        for (int m = 1; m < 16; m <<= 1) {
            int ov = __shfl_xor(v, m, 64);
            int oi = __shfl_xor(ci, m, 64);
            bool take = (ov > v) || (ov == v && oi < ci);
            v  = take ? ov : v;
            ci = take ? oi : ci;
        }
        if (l16 == 0) {
            const int r = wrow0 + (slot >> 2) * 16 + quad * 4 + (slot & 3);
            unsigned u = ((unsigned)v) ^ 0x80000000u;    // monotone int -> unsigned
            unsigned long long key = ((unsigned long long)u << 32) | (unsigned)(~ci);
            atomicMax(best + r, key);
        }
    }
}

// ---------------- kernel 3: loss from keys (R10, measured; absmax 0.0) ----------------
__global__ __launch_bounds__(256) void loss_kernel(const float* __restrict__ qninv,
                                                   const unsigned long long* __restrict__ best,
                                                   float* __restrict__ out, int N) {
    __shared__ float part[4];
    const int wave = threadIdx.x >> 6, lane = threadIdx.x & 63;
    const int gtid = blockIdx.x * 256 + threadIdx.x;
    const int stride = gridDim.x * 256;
    float local = 0.f;
    for (int row = gtid; row < N; row += stride) {
        unsigned long long key = best[row];
        int j = (int)(~(unsigned)(key & 0xffffffffull));
        int v = (int)(((unsigned)(key >> 32)) ^ 0x80000000u);
        float c = (float)v * qninv[row] * qninv[j];
        float s = fmaxf(2.f - 2.f * c, 0.f);
        local += -logf(sqrtf(s) + EPS);
    }
#pragma unroll
    for (int off = 32; off > 0; off >>= 1) local += __shfl_down(local, off, 64);
    if (lane == 0) part[wave] = local;
    __syncthreads();
    if (threadIdx.x == 0)
        atomicAdd(out, (part[0] + part[1] + part[2] + part[3]) / (float)N);
}

extern "C" void kernel_launch(void* const* d_in, const int* in_sizes, int n_in,
                              void* d_out, int out_size, void* d_ws, size_t ws_size,
                              hipStream_t stream) {
    const float* in = (const float*)d_in[0];
    float* out = (float*)d_out;
    const int N = in_sizes[0] / D;                   // 8192

    // workspace layout: qninv (N f32) | best (N u64) | xq (N*D i8)
    char* ws = (char*)d_ws;
    float* qninv = (float*)ws;
    unsigned long long* best = (unsigned long long*)(ws + 64 * 1024);
    char* xq = ws + 192 * 1024;

    prep_kernel<<<N / 4, 256, 0, stream>>>(in, qninv, xq, best, out, N);
    maxdot_rows<<<1024, 256, 0, stream>>>(xq, best);       // 32 rb x 32 cs
    loss_kernel<<<16, 256, 0, stream>>>(qninv, best, out, N);
}

// Round 13
// 99.051 us; speedup vs baseline: 1.1628x; 1.1628x over previous
//
#include <hip/hip_runtime.h>
#include <hip/hip_bf16.h>
#include <math.h>

#define D 384
#define EPS 1e-8f

#define RPB 256            // rows per block (4 waves x 64) -- reuse-optimal
#define CPS 512            // cols per split
#define POS_W 128          // cols per position (fold granularity)
#define NPOS 4             // 512/128
#define NKB 6              // 384/64 k-steps (i8: K=64 per MFMA)
#define NT  24             // NPOS * NKB tiles per block
#define STG 24576          // stage bytes: 8 KB B (128 cols x 64 B) + 16 KB A (256 rows x 64 B)

typedef int    intx4   __attribute__((ext_vector_type(4)));

// ---------------- kernel 1: i8 quant + qninv + ws init (measured) ----------------
// Rows unit-norm -> scale 127 preserves dot ranking. qninv = 1/||q|| lets the
// loss kernel reconstruct cosine from the integer dot in the key.
__global__ __launch_bounds__(256) void prep_kernel(const float* __restrict__ in,
                                                   float* __restrict__ qninv,
                                                   char* __restrict__ xq,
                                                   unsigned long long* __restrict__ best,
                                                   float* __restrict__ out, int N) {
    if (blockIdx.x == 0 && threadIdx.x == 0) *out = 0.f;   // replaces memset node
    int row = blockIdx.x * 4 + (threadIdx.x >> 6);   // one wave per row
    if (row >= N) return;
    int lane = threadIdx.x & 63;
    const float* p = in + (size_t)row * D;
    float4 a = *(const float4*)(p + lane * 4);           // elems 0..255
    float2 b = *(const float2*)(p + 256 + lane * 2);     // elems 256..383
    float s = a.x * a.x + a.y * a.y + a.z * a.z + a.w * a.w + b.x * b.x + b.y * b.y;
#pragma unroll
    for (int off = 32; off >= 1; off >>= 1) s += __shfl_xor(s, off, 64);
    float rn = 1.0f / fmaxf(sqrtf(s), EPS);
    const float sc = rn * 127.f;
    int b0 = __float2int_rn(a.x * sc), b1 = __float2int_rn(a.y * sc);
    int b2 = __float2int_rn(a.z * sc), b3 = __float2int_rn(a.w * sc);
    int b4 = __float2int_rn(b.x * sc), b5 = __float2int_rn(b.y * sc);
    char* q = xq + (size_t)row * D;
    *(int*)(q + lane * 4) = (b0 & 0xff) | ((b1 & 0xff) << 8) | ((b2 & 0xff) << 16) | (b3 << 24);
    *(short*)(q + 256 + lane * 2) = (short)((b4 & 0xff) | (b5 << 8));
    int qs = b0 * b0 + b1 * b1 + b2 * b2 + b3 * b3 + b4 * b4 + b5 * b5;
#pragma unroll
    for (int off = 32; off >= 1; off >>= 1) qs += __shfl_xor(qs, off, 64);
    if (lane == 0) { qninv[row] = 1.0f / sqrtf((float)qs); best[row] = 0ull; }
}

// ---------------- kernel 2: row-ownership i8-MFMA scan (best-measured, ~41 us) ----------------
// Settled structure after 6 structural experiments (R5/R7/R9/R10/R12 all
// regressed; see session journal):
//  - A AND B cooperatively staged through LDS via global_load_lds (6 glds/
//    thread, 24 KB/stage, 3-buffer rotation, staged 2 ahead). Reg-A variants
//    regress: A's consume-wait on the global queue costs more than the LDS
//    round-trip; shared stage keeps ONE latency exposure per step.
//  - runtime-tt loop + pointer rotation (full unroll spills acc to scratch).
//  - counted vmcnt(6): stage(tt+1) stays in flight across the barrier.
//  - all 12 frag ds_reads issued together; mi-outer MFMA.
//  - occupancy is hard-capped at 2 waves/SIMD by acc[4][8] (128 AGPR) + ~110
//    arch VGPRs on the unified file; smaller output tiles lose B-reuse faster
//    than they gain latency hiding (R9, R12).
// Do not unroll; do not add setprio; do not shrink RPB or POS_W.
__global__ __launch_bounds__(256, 2) void maxdot_rows(const char* __restrict__ xq,
                                                      unsigned long long* __restrict__ best) {
    __shared__ char Bs[3][STG];

    const int t    = threadIdx.x;
    const int lane = t & 63;
    const int wv   = t >> 6;
    const int quad = lane >> 4, l16 = lane & 15;
    const int rb   = blockIdx.x >> 4;                // 32 row-blocks
    const int cs   = blockIdx.x & 15;                // 16 col-splits
    const int row0b = rb * RPB;
    const int col0s = cs * CPS;
    const int wrow0 = row0b + wv * 64;

    intx4 acc[4][8];
#pragma unroll
    for (int mi = 0; mi < 4; ++mi)
#pragma unroll
        for (int ni = 0; ni < 8; ++ni) acc[mi][ni] = (intx4){0, 0, 0, 0};

    int rv[16];
    int ri[16];
#pragma unroll
    for (int i = 0; i < 16; ++i) { rv[i] = -0x7fffffff; ri[i] = 0; }

    // staging: thread t owns granule sg = t&3 of B-cols {sc, sc+64} and
    // A-rows {sc, sc+64, sc+128, sc+192}, sc = t>>2. 6 x 16 B = 96 B/thread.
    const int sc = t >> 2;
    const int sg = t & 3;

#define GLDS(SRC, DST) __builtin_amdgcn_global_load_lds(                               \
        (const __attribute__((address_space(1))) void*)(SRC),                          \
        (__attribute__((address_space(3))) void*)(DST), 16, 0, 0)

#define STAGE(TT, BUF) do {                                                            \
        const int p_  = (TT) / NKB, kb_ = (TT) - p_ * NKB;                             \
        const int cb_ = col0s + p_ * POS_W;                                            \
        const size_t ko_ = (size_t)kb_ * 64 + sg * 16;                                 \
        GLDS(xq + (size_t)(cb_ + sc)        * 384 + ko_, (BUF) +         t * 16);      \
        GLDS(xq + (size_t)(cb_ + 64 + sc)   * 384 + ko_, (BUF) +  4096 + t * 16);      \
        GLDS(xq + (size_t)(row0b + sc)      * 384 + ko_, (BUF) +  8192 + t * 16);      \
        GLDS(xq + (size_t)(row0b + 64 + sc) * 384 + ko_, (BUF) + 12288 + t * 16);      \
        GLDS(xq + (size_t)(row0b + 128 + sc)* 384 + ko_, (BUF) + 16384 + t * 16);      \
        GLDS(xq + (size_t)(row0b + 192 + sc)* 384 + ko_, (BUF) + 20480 + t * 16);      \
    } while (0)

    // prologue: 2 stages (12 glds) in flight
    STAGE(0, Bs[0]);
    STAGE(1, Bs[1]);

    char* b0 = Bs[0];                                // read this iter
    char* b1 = Bs[1];                                // read next iter
    char* b2 = Bs[2];                                // stage target this iter

    const int lofs = l16 * 64 + quad * 16;           // reader byte within a 64-B k-chunk

    for (int tt = 0; tt < NT; ++tt) {
        const int pos = tt / NKB, kb = tt - pos * NKB;
        const int colbase = col0s + pos * POS_W;

        // stage(tt) complete; stage(tt+1) (6 glds) stays in flight across barrier
        if (tt < NT - 1) asm volatile("s_waitcnt vmcnt(6)" ::: "memory");
        else             asm volatile("s_waitcnt vmcnt(0)" ::: "memory");
        __builtin_amdgcn_s_barrier();
        __builtin_amdgcn_sched_barrier(0);

        // stage tile tt+2 into the buffer all waves finished reading at tt-1
        if (tt + 2 < NT) STAGE(tt + 2, b2);

        // A and B fragments from LDS (prefetched ~2 k-steps ago); all 12
        // ds_reads issued together -> single latency exposure
        const char* Ab = b0 + 8192 + wv * 4096;      // this wave's 64 rows
        intx4 af[4];
#pragma unroll
        for (int mi = 0; mi < 4; ++mi)
            af[mi] = *(const intx4*)(Ab + mi * 1024 + lofs);
        intx4 bfr[8];
#pragma unroll
        for (int ni = 0; ni < 8; ++ni)
            bfr[ni] = *(const intx4*)(b0 + ni * 1024 + lofs);
#pragma unroll
        for (int mi = 0; mi < 4; ++mi)
#pragma unroll
            for (int ni = 0; ni < 8; ++ni)
                acc[mi][ni] = __builtin_amdgcn_mfma_i32_16x16x64_i8(af[mi], bfr[ni], acc[mi][ni], 0, 0, 0);

        // ---- end of a position: fold into running (val, col); zero acc ----
        if (kb == NKB - 1) {
            const bool dg = (colbase < row0b + RPB) && (row0b < colbase + POS_W);
#pragma unroll
            for (int mi = 0; mi < 4; ++mi)
#pragma unroll
                for (int reg = 0; reg < 4; ++reg) {
                    const int r = wrow0 + mi * 16 + quad * 4 + reg;
                    int d[8];
#pragma unroll
                    for (int ni = 0; ni < 8; ++ni) d[ni] = acc[mi][ni][reg];
                    if (dg) {
#pragma unroll
                        for (int ni = 0; ni < 8; ++ni)
                            if (colbase + ni * 16 + l16 == r) d[ni] = -0x40000000;
                    }
                    int m = d[0]; int ci = 0;
#pragma unroll
                    for (int ni = 1; ni < 8; ++ni) {     // ties -> lower ni (lower col)
                        bool gt = d[ni] > m;
                        m  = gt ? d[ni] : m;
                        ci = gt ? ni : ci;
                    }
                    const int slot = mi * 4 + reg;
                    bool upd = m > rv[slot];             // ties -> earlier position (lower col)
                    rv[slot] = upd ? m : rv[slot];
                    ri[slot] = upd ? (colbase + ci * 16 + l16) : ri[slot];
#pragma unroll
                    for (int ni = 0; ni < 8; ++ni) acc[mi][ni][reg] = 0;
                }
        }

        // rotate buffers
        char* tmp = b0; b0 = b1; b1 = b2; b2 = tmp;
    }
#undef STAGE
#undef GLDS

    // ---- final row-side reduce over the 16 col-lanes, one atomic per row ----
#pragma unroll
    for (int slot = 0; slot < 16; ++slot) {
        int v = rv[slot]; int ci = ri[slot];
#pragma unroll
        for (int m = 1; m < 16; m <<= 1) {
            int ov = __shfl_xor(v, m, 64);
            int oi = __shfl_xor(ci, m, 64);
            bool take = (ov > v) || (ov == v && oi < ci);
            v  = take ? ov : v;
            ci = take ? oi : ci;
        }
        if (l16 == 0) {
            const int r = wrow0 + (slot >> 2) * 16 + quad * 4 + (slot & 3);
            unsigned u = ((unsigned)v) ^ 0x80000000u;    // monotone int -> unsigned
            unsigned long long key = ((unsigned long long)u << 32) | (unsigned)(~ci);
            atomicMax(best + r, key);
        }
    }
}

// ---------------- kernel 3: loss from keys (measured; absmax 0.0) ----------------
// Unit-norm rows: ||x-y||^2 = 2-2*cos; cos = v * qninv_i * qninv_j where v is
// the integer dot packed in the winning key.
__global__ __launch_bounds__(256) void loss_kernel(const float* __restrict__ qninv,
                                                   const unsigned long long* __restrict__ best,
                                                   float* __restrict__ out, int N) {
    __shared__ float part[4];
    const int wave = threadIdx.x >> 6, lane = threadIdx.x & 63;
    const int gtid = blockIdx.x * 256 + threadIdx.x;
    const int stride = gridDim.x * 256;
    float local = 0.f;
    for (int row = gtid; row < N; row += stride) {
        unsigned long long key = best[row];
        int j = (int)(~(unsigned)(key & 0xffffffffull));
        int v = (int)(((unsigned)(key >> 32)) ^ 0x80000000u);
        float c = (float)v * qninv[row] * qninv[j];
        float s = fmaxf(2.f - 2.f * c, 0.f);
        local += -logf(sqrtf(s) + EPS);
    }
#pragma unroll
    for (int off = 32; off > 0; off >>= 1) local += __shfl_down(local, off, 64);
    if (lane == 0) part[wave] = local;
    __syncthreads();
    if (threadIdx.x == 0)
        atomicAdd(out, (part[0] + part[1] + part[2] + part[3]) / (float)N);
}

extern "C" void kernel_launch(void* const* d_in, const int* in_sizes, int n_in,
                              void* d_out, int out_size, void* d_ws, size_t ws_size,
                              hipStream_t stream) {
    const float* in = (const float*)d_in[0];
    float* out = (float*)d_out;
    const int N = in_sizes[0] / D;                   // 8192

    // workspace layout: qninv (N f32) | best (N u64) | xq (N*D i8)
    char* ws = (char*)d_ws;
    float* qninv = (float*)ws;
    unsigned long long* best = (unsigned long long*)(ws + 64 * 1024);
    char* xq = ws + 192 * 1024;

    prep_kernel<<<N / 4, 256, 0, stream>>>(in, qninv, xq, best, out, N);
    maxdot_rows<<<512, 256, 0, stream>>>(xq, best);        // 32 rb x 16 cs, full grid
    loss_kernel<<<16, 256, 0, stream>>>(qninv, best, out, N);
}